// Round 1
// baseline (3520.366 us; speedup 1.0000x reference)
//
#include <hip/hip_runtime.h>
#include <math.h>

// Problem constants
#define NP   100000
#define EDG  1600000
#define NK   15
#define SIGK 0.04f

__device__ __forceinline__ float lk(float v) { return v >= 0.f ? v : 0.1f * v; }

// ---------------------------------------------------------------------------
// Tiled fp32 GEMM: T[r][c0..c0+63] = X[r][:] @ W[:, c0..c0+63]
// Block: 256 thr, 64 rows x 64 cols, thread tile 4x4. K staged in 64-chunks
// so static LDS stays <64KB (xl 33.8KB + wl 16KB).
// TRANS: apply z = leaky(ta[c]*v + tb[c]) to X elements on load (BN+LeakyReLU).
// ---------------------------------------------------------------------------
template <int KIN, bool TRANS>
__global__ __launch_bounds__(256) void gemm_k(const float* __restrict__ X,
                                              const float* __restrict__ W,
                                              float* __restrict__ T, int n, int cout,
                                              const float* __restrict__ ta,
                                              const float* __restrict__ tb) {
  constexpr int XS = KIN + 4;  // pad 4 -> banks (4r+i)%32, worst 2-way (free)
  __shared__ float xl[64 * XS];
  __shared__ float wl[64 * 64];
  const int tid = threadIdx.x;
  const int r0 = blockIdx.x << 6;
  const int c0 = blockIdx.y << 6;

  // stage X tile (64 rows x KIN), float4 coalesced
  constexpr int QK = KIN >> 2;
  for (int idx = tid; idx < 64 * QK; idx += 256) {
    const int r = idx / QK, q = (idx - r * QK) << 2;
    const int row = r0 + r;
    float4 v = make_float4(0.f, 0.f, 0.f, 0.f);
    if (row < n) v = *(const float4*)&X[(size_t)row * KIN + q];
    if (TRANS) {
      v.x = lk(ta[q + 0] * v.x + tb[q + 0]);
      v.y = lk(ta[q + 1] * v.y + tb[q + 1]);
      v.z = lk(ta[q + 2] * v.z + tb[q + 2]);
      v.w = lk(ta[q + 3] * v.w + tb[q + 3]);
    }
    *(float4*)&xl[r * XS + q] = v;
  }

  const int rg = (tid >> 4) << 2;
  const int cg = (tid & 15) << 2;
  float4 a0 = make_float4(0.f, 0.f, 0.f, 0.f), a1 = a0, a2 = a0, a3 = a0;

  for (int kc = 0; kc < KIN; kc += 64) {
    // stage W rows kc..kc+63 for this 64-col block
    for (int idx = tid; idx < 1024; idx += 256) {
      const int i = idx >> 4, q = (idx & 15) << 2;
      *(float4*)&wl[i * 64 + q] = *(const float4*)&W[(size_t)(kc + i) * cout + c0 + q];
    }
    __syncthreads();  // covers X staging on first pass too
#pragma unroll 8
    for (int i = 0; i < 64; ++i) {
      const float4 w = *(float4*)&wl[i * 64 + cg];
      const float x0 = xl[(rg + 0) * XS + kc + i];
      const float x1 = xl[(rg + 1) * XS + kc + i];
      const float x2 = xl[(rg + 2) * XS + kc + i];
      const float x3 = xl[(rg + 3) * XS + kc + i];
      a0.x += x0 * w.x; a0.y += x0 * w.y; a0.z += x0 * w.z; a0.w += x0 * w.w;
      a1.x += x1 * w.x; a1.y += x1 * w.y; a1.z += x1 * w.z; a1.w += x1 * w.w;
      a2.x += x2 * w.x; a2.y += x2 * w.y; a2.z += x2 * w.z; a2.w += x2 * w.w;
      a3.x += x3 * w.x; a3.y += x3 * w.y; a3.z += x3 * w.z; a3.w += x3 * w.w;
    }
    __syncthreads();  // protect wl overwrite
  }

  float4 accs[4] = {a0, a1, a2, a3};
#pragma unroll
  for (int r = 0; r < 4; ++r) {
    const int row = r0 + rg + r;
    if (row < n) *(float4*)&T[(size_t)row * cout + c0 + cg] = accs[r];
  }
}

// ---------------------------------------------------------------------------
// Column sums / sums-of-squares for BN stats. stride % C == 0 so each thread's
// elements share one column. Block-reduce then 2 atomics per column per block.
// ---------------------------------------------------------------------------
template <int C>
__global__ __launch_bounds__(256) void colstats_k(const float* __restrict__ T, int total,
                                                  float* __restrict__ sum,
                                                  float* __restrict__ sq) {
  __shared__ float s1[256], s2[256];
  const int tid = threadIdx.x;
  const int stride = gridDim.x << 8;
  float a = 0.f, b = 0.f;
  for (int idx = (blockIdx.x << 8) + tid; idx < total; idx += stride) {
    const float v = T[idx];
    a += v;
    b += v * v;
  }
  s1[tid] = a;
  s2[tid] = b;
  __syncthreads();
  for (int s = 128; s >= C; s >>= 1) {
    if (tid < s) {
      s1[tid] += s1[tid + s];
      s2[tid] += s2[tid + s];
    }
    __syncthreads();
  }
  if (tid < C) {
    atomicAdd(&sum[tid], s1[tid]);
    atomicAdd(&sq[tid], s2[tid]);
  }
}

// Fold BN into per-channel affine: a = g/sqrt(var+eps), b = beta - mean*a
__global__ void finalize_k(const float* __restrict__ sum, const float* __restrict__ sq,
                           const float* __restrict__ g, const float* __restrict__ b,
                           float* __restrict__ oa, float* __restrict__ ob, int C,
                           float invn) {
  const int c = threadIdx.x;
  if (c < C) {
    const float m = sum[c] * invn;
    const float var = sq[c] * invn - m * m;
    const float a = g[c] / sqrtf(var + 1e-5f);
    oa[c] = a;
    ob[c] = b[c] - m * a;
  }
}

// In-place h = leaky(a*h + b), 64 channels, float4
__global__ __launch_bounds__(256) void normleaky_k(float* __restrict__ t,
                                                   const float* __restrict__ a,
                                                   const float* __restrict__ b) {
  const int idx = (blockIdx.x << 8) + threadIdx.x;
  const int c = (idx << 2) & 63;
  float4 v = ((float4*)t)[idx];
  v.x = lk(a[c + 0] * v.x + b[c + 0]);
  v.y = lk(a[c + 1] * v.y + b[c + 1]);
  v.z = lk(a[c + 2] * v.z + b[c + 2]);
  v.w = lk(a[c + 3] * v.w + b[c + 3]);
  ((float4*)t)[idx] = v;
}

// out = leaky(a2*t2 + b2) + (asc*tsc + bsc), 256 channels, in-place on d_out
__global__ __launch_bounds__(256) void final_k(float* __restrict__ o,
                                               const float* __restrict__ sc,
                                               const float* __restrict__ a2,
                                               const float* __restrict__ b2,
                                               const float* __restrict__ asc,
                                               const float* __restrict__ bsc) {
  const int idx = (blockIdx.x << 8) + threadIdx.x;
  const int c = (idx << 2) & 255;
  float4 t = ((float4*)o)[idx];
  float4 s = ((const float4*)sc)[idx];
  float4 r;
  r.x = lk(a2[c + 0] * t.x + b2[c + 0]) + asc[c + 0] * s.x + bsc[c + 0];
  r.y = lk(a2[c + 1] * t.y + b2[c + 1]) + asc[c + 1] * s.y + bsc[c + 1];
  r.z = lk(a2[c + 2] * t.z + b2[c + 2]) + asc[c + 2] * s.z + bsc[c + 2];
  r.w = lk(a2[c + 3] * t.w + b2[c + 3]) + asc[c + 3] * s.w + bsc[c + 3];
  ((float4*)o)[idx] = r;
}

// ---------------------------------------------------------------------------
// KPConv: block = 512 thr handles 128 edges. Phase 1: compute influences,
// compact active (edge,k) pairs into per-k LDS lists; stage neighbor features
// f (128x64) in LDS. Phase 2: per k, stage W_k (64x64) in LDS, list-indirected
// mini-GEMM (thread = 1 edge x 4 cols), scatter infl-scaled results into y via
// device-scope float atomics (y is 25.6MB -> L2-resident RMW).
// Sparsity: typically only ~1-3 of 15 kernel points influence an edge.
// Static LDS = 62,976 B (<64KB) -> 2 blocks/CU.
// ---------------------------------------------------------------------------
__global__ __launch_bounds__(512) void kpconv_k(const float* __restrict__ pos,
                                                const int* __restrict__ eref,
                                                const int* __restrict__ equery,
                                                const float* __restrict__ kpts,
                                                const float* __restrict__ Wkp,
                                                const float* __restrict__ h,
                                                float* __restrict__ y) {
  __shared__ float fl[128 * 65];        // features, pad 65 -> bank (slot+i)%32
  __shared__ float wl[64 * 64];         // W_k tile
  __shared__ float infl[128 * 16];      // influence per (slot,k)
  __shared__ unsigned short lst[NK * 128];
  __shared__ int eq_s[128];
  __shared__ int er_s[128];
  __shared__ float kp_s[48];
  __shared__ int cnt[NK];

  const int tid = threadIdx.x;
  const int base = blockIdx.x << 7;  // E = 12500*128 exactly

  if (tid < 128) {
    er_s[tid] = eref[base + tid];
    eq_s[tid] = equery[base + tid];
  }
  if (tid < NK * 3) kp_s[tid] = kpts[tid];
  if (tid < NK) cnt[tid] = 0;
  __syncthreads();

  // influences + list compaction (threads 0..127, one edge each)
  if (tid < 128) {
    const int er = er_s[tid], eq = eq_s[tid];
    const float rx = pos[er * 4 + 1] - pos[eq * 4 + 1];
    const float ry = pos[er * 4 + 2] - pos[eq * 4 + 2];
    const float rz = pos[er * 4 + 3] - pos[eq * 4 + 3];
#pragma unroll
    for (int k = 0; k < NK; ++k) {
      const float dx = rx - kp_s[k * 3 + 0];
      const float dy = ry - kp_s[k * 3 + 1];
      const float dz = rz - kp_s[k * 3 + 2];
      const float w = 1.f - sqrtf(dx * dx + dy * dy + dz * dz) * (1.f / SIGK);
      infl[tid * 16 + k] = w;
      if (w > 0.f) {
        const int p = atomicAdd(&cnt[k], 1);
        lst[k * 128 + p] = (unsigned short)tid;
      }
    }
  }
  // stage features: h[e_ref] rows, 128 edges x 16 float4
  for (int idx = tid; idx < 2048; idx += 512) {
    const int s = idx >> 4, q = (idx & 15) << 2;
    const float4 v = *(const float4*)&h[(size_t)er_s[s] * 64 + q];
    float* d = &fl[s * 65 + q];
    d[0] = v.x; d[1] = v.y; d[2] = v.z; d[3] = v.w;
  }
  __syncthreads();

  const int jt = tid >> 4;         // 0..31 edge slots per pass
  const int ct = (tid & 15) << 2;  // 4-col group
  for (int k = 0; k < NK; ++k) {
    for (int idx = tid; idx < 1024; idx += 512) {
      *(float4*)&wl[idx << 2] = *(const float4*)&Wkp[k * 4096 + (idx << 2)];
    }
    __syncthreads();
    const int na = cnt[k];  // uniform
    for (int j0 = 0; j0 < na; j0 += 32) {
      const int j = j0 + jt;
      const bool valid = j < na;
      const int slot = valid ? (int)lst[k * 128 + j] : 0;
      float4 a = make_float4(0.f, 0.f, 0.f, 0.f);
#pragma unroll 8
      for (int i = 0; i < 64; ++i) {
        const float fv = fl[slot * 65 + i];
        const float4 w = *(float4*)&wl[i * 64 + ct];
        a.x += fv * w.x; a.y += fv * w.y; a.z += fv * w.z; a.w += fv * w.w;
      }
      if (valid) {
        const float wk = infl[slot * 16 + k];
        float* dst = &y[(size_t)eq_s[slot] * 64 + ct];
        atomicAdd(&dst[0], wk * a.x);
        atomicAdd(&dst[1], wk * a.y);
        atomicAdd(&dst[2], wk * a.z);
        atomicAdd(&dst[3], wk * a.w);
      }
    }
    __syncthreads();
  }
}

// ---------------------------------------------------------------------------
extern "C" void kernel_launch(void* const* d_in, const int* in_sizes, int n_in,
                              void* d_out, int out_size, void* d_ws, size_t ws_size,
                              hipStream_t stream) {
  const float* pos = (const float*)d_in[0];
  const float* x   = (const float*)d_in[1];
  const int* er    = (const int*)d_in[2];
  const int* eq    = (const int*)d_in[3];
  const float* W1  = (const float*)d_in[4];
  const float* g1  = (const float*)d_in[5];
  const float* b1  = (const float*)d_in[6];
  const float* kp  = (const float*)d_in[7];
  const float* Wkp = (const float*)d_in[8];
  const float* gkp = (const float*)d_in[9];
  const float* bkp = (const float*)d_in[10];
  const float* W2  = (const float*)d_in[11];
  const float* g2  = (const float*)d_in[12];
  const float* b2  = (const float*)d_in[13];
  const float* Wsc = (const float*)d_in[14];
  const float* gsc = (const float*)d_in[15];
  const float* bsc = (const float*)d_in[16];
  float* out = (float*)d_out;
  float* ws = (float*)d_ws;

  // workspace layout (floats)
  float* sum1 = ws;          float* sq1  = ws + 64;
  float* sumsc = ws + 128;   float* sqsc = ws + 384;
  float* sumy = ws + 640;    float* sqy  = ws + 704;
  float* sum2 = ws + 768;    float* sq2  = ws + 1024;
  float* a1v = ws + 1280;    float* b1v  = ws + 1344;
  float* ascv = ws + 1408;   float* bscv = ws + 1664;
  float* ayv = ws + 1920;    float* byv  = ws + 1984;
  float* a2v = ws + 2048;    float* b2v  = ws + 2304;
  float* ybuf = ws + 4096;                    // [N,64]
  float* hbuf = ybuf + (size_t)NP * 64;       // [N,64]
  float* tsc  = hbuf + (size_t)NP * 64;       // [N,256]

  // zero stats block + y (atomic target)
  (void)hipMemsetAsync(d_ws, 0, (4096 + (size_t)NP * 64) * sizeof(float), stream);

  const float invn = 1.f / (float)NP;

  // unary_1: t1 = x@W1 ; BN stats ; fold ; h = leaky(BN(t1)) in place
  gemm_k<128, false><<<dim3(1563, 1), 256, 0, stream>>>(x, W1, hbuf, NP, 64, nullptr, nullptr);
  colstats_k<64><<<512, 256, 0, stream>>>(hbuf, NP * 64, sum1, sq1);
  finalize_k<<<1, 256, 0, stream>>>(sum1, sq1, g1, b1, a1v, b1v, 64, invn);
  normleaky_k<<<6250, 256, 0, stream>>>(hbuf, a1v, b1v);

  // shortcut: tsc = x@Wsc ; stats ; fold
  gemm_k<128, false><<<dim3(1563, 4), 256, 0, stream>>>(x, Wsc, tsc, NP, 256, nullptr, nullptr);
  colstats_k<256><<<512, 256, 0, stream>>>(tsc, NP * 256, sumsc, sqsc);
  finalize_k<<<1, 256, 0, stream>>>(sumsc, sqsc, gsc, bsc, ascv, bscv, 256, invn);

  // KPConv: y += scatter(infl * h[e_ref] @ W_k)
  kpconv_k<<<12500, 512, 0, stream>>>(pos, er, eq, kp, Wkp, hbuf, ybuf);
  colstats_k<64><<<512, 256, 0, stream>>>(ybuf, NP * 64, sumy, sqy);
  finalize_k<<<1, 256, 0, stream>>>(sumy, sqy, gkp, bkp, ayv, byv, 64, invn);

  // unary_2: t2 = leaky(BN(y)) @ W2  (BN+leaky fused into GEMM input load)
  // t2 staged directly in d_out
  gemm_k<64, true><<<dim3(1563, 4), 256, 0, stream>>>(ybuf, W2, out, NP, 256, ayv, byv);
  colstats_k<256><<<512, 256, 0, stream>>>(out, NP * 256, sum2, sq2);
  finalize_k<<<1, 256, 0, stream>>>(sum2, sq2, g2, b2, a2v, b2v, 256, invn);

  // out = leaky(BN(t2)) + BN(tsc)
  final_k<<<25000, 256, 0, stream>>>(out, tsc, a2v, b2v, ascv, bscv);
}

// Round 2
// 1191.320 us; speedup vs baseline: 2.9550x; 2.9550x over previous
//
#include <hip/hip_runtime.h>
#include <math.h>

#define NP   100000
#define EDG  1600000
#define NK   15
#define SIGK 0.04f
#define SCH  2048          // scan chunk
#define SNB  49            // ceil(NP/SCH)
#define AK   68            // padded agg row (floats) to break bank conflicts

typedef __bf16 v8bf __attribute__((ext_vector_type(8)));
typedef float  v4f  __attribute__((ext_vector_type(4)));

__device__ __forceinline__ float lk(float v) { return v >= 0.f ? v : 0.1f * v; }

// ---------------------------------------------------------------------------
// Tiled fp32 GEMM (unchanged from R1): 64x64 tile, 4x4 per thread.
// TRANS fuses leaky(a*x+b) into the X load.
// ---------------------------------------------------------------------------
template <int KIN, bool TRANS>
__global__ __launch_bounds__(256) void gemm_k(const float* __restrict__ X,
                                              const float* __restrict__ W,
                                              float* __restrict__ T, int n, int cout,
                                              const float* __restrict__ ta,
                                              const float* __restrict__ tb) {
  constexpr int XS = KIN + 4;
  __shared__ float xl[64 * XS];
  __shared__ float wl[64 * 64];
  const int tid = threadIdx.x;
  const int r0 = blockIdx.x << 6;
  const int c0 = blockIdx.y << 6;

  constexpr int QK = KIN >> 2;
  for (int idx = tid; idx < 64 * QK; idx += 256) {
    const int r = idx / QK, q = (idx - r * QK) << 2;
    const int row = r0 + r;
    float4 v = make_float4(0.f, 0.f, 0.f, 0.f);
    if (row < n) v = *(const float4*)&X[(size_t)row * KIN + q];
    if (TRANS) {
      v.x = lk(ta[q + 0] * v.x + tb[q + 0]);
      v.y = lk(ta[q + 1] * v.y + tb[q + 1]);
      v.z = lk(ta[q + 2] * v.z + tb[q + 2]);
      v.w = lk(ta[q + 3] * v.w + tb[q + 3]);
    }
    *(float4*)&xl[r * XS + q] = v;
  }

  const int rg = (tid >> 4) << 2;
  const int cg = (tid & 15) << 2;
  float4 a0 = make_float4(0.f, 0.f, 0.f, 0.f), a1 = a0, a2 = a0, a3 = a0;

  for (int kc = 0; kc < KIN; kc += 64) {
    for (int idx = tid; idx < 1024; idx += 256) {
      const int i = idx >> 4, q = (idx & 15) << 2;
      *(float4*)&wl[i * 64 + q] = *(const float4*)&W[(size_t)(kc + i) * cout + c0 + q];
    }
    __syncthreads();
#pragma unroll 8
    for (int i = 0; i < 64; ++i) {
      const float4 w = *(float4*)&wl[i * 64 + cg];
      const float x0 = xl[(rg + 0) * XS + kc + i];
      const float x1 = xl[(rg + 1) * XS + kc + i];
      const float x2 = xl[(rg + 2) * XS + kc + i];
      const float x3 = xl[(rg + 3) * XS + kc + i];
      a0.x += x0 * w.x; a0.y += x0 * w.y; a0.z += x0 * w.z; a0.w += x0 * w.w;
      a1.x += x1 * w.x; a1.y += x1 * w.y; a1.z += x1 * w.z; a1.w += x1 * w.w;
      a2.x += x2 * w.x; a2.y += x2 * w.y; a2.z += x2 * w.z; a2.w += x2 * w.w;
      a3.x += x3 * w.x; a3.y += x3 * w.y; a3.z += x3 * w.z; a3.w += x3 * w.w;
    }
    __syncthreads();
  }

  float4 accs[4] = {a0, a1, a2, a3};
#pragma unroll
  for (int r = 0; r < 4; ++r) {
    const int row = r0 + rg + r;
    if (row < n) *(float4*)&T[(size_t)row * cout + c0 + cg] = accs[r];
  }
}

// ---------------------------------------------------------------------------
// BN stats + fold (unchanged)
// ---------------------------------------------------------------------------
template <int C>
__global__ __launch_bounds__(256) void colstats_k(const float* __restrict__ T, int total,
                                                  float* __restrict__ sum,
                                                  float* __restrict__ sq) {
  __shared__ float s1[256], s2[256];
  const int tid = threadIdx.x;
  const int stride = gridDim.x << 8;
  float a = 0.f, b = 0.f;
  for (int idx = (blockIdx.x << 8) + tid; idx < total; idx += stride) {
    const float v = T[idx];
    a += v;
    b += v * v;
  }
  s1[tid] = a;
  s2[tid] = b;
  __syncthreads();
  for (int s = 128; s >= C; s >>= 1) {
    if (tid < s) {
      s1[tid] += s1[tid + s];
      s2[tid] += s2[tid + s];
    }
    __syncthreads();
  }
  if (tid < C) {
    atomicAdd(&sum[tid], s1[tid]);
    atomicAdd(&sq[tid], s2[tid]);
  }
}

__global__ void finalize_k(const float* __restrict__ sum, const float* __restrict__ sq,
                           const float* __restrict__ g, const float* __restrict__ b,
                           float* __restrict__ oa, float* __restrict__ ob, int C,
                           float invn) {
  const int c = threadIdx.x;
  if (c < C) {
    const float m = sum[c] * invn;
    const float var = sq[c] * invn - m * m;
    const float a = g[c] / sqrtf(var + 1e-5f);
    oa[c] = a;
    ob[c] = b[c] - m * a;
  }
}

__global__ __launch_bounds__(256) void normleaky_k(float* __restrict__ t,
                                                   const float* __restrict__ a,
                                                   const float* __restrict__ b) {
  const int idx = (blockIdx.x << 8) + threadIdx.x;
  const int c = (idx << 2) & 63;
  float4 v = ((float4*)t)[idx];
  v.x = lk(a[c + 0] * v.x + b[c + 0]);
  v.y = lk(a[c + 1] * v.y + b[c + 1]);
  v.z = lk(a[c + 2] * v.z + b[c + 2]);
  v.w = lk(a[c + 3] * v.w + b[c + 3]);
  ((float4*)t)[idx] = v;
}

__global__ __launch_bounds__(256) void final_k(float* __restrict__ o,
                                               const float* __restrict__ sc,
                                               const float* __restrict__ a2,
                                               const float* __restrict__ b2,
                                               const float* __restrict__ asc,
                                               const float* __restrict__ bsc) {
  const int idx = (blockIdx.x << 8) + threadIdx.x;
  const int c = (idx << 2) & 255;
  float4 t = ((float4*)o)[idx];
  float4 s = ((const float4*)sc)[idx];
  float4 r;
  r.x = lk(a2[c + 0] * t.x + b2[c + 0]) + asc[c + 0] * s.x + bsc[c + 0];
  r.y = lk(a2[c + 1] * t.y + b2[c + 1]) + asc[c + 1] * s.y + bsc[c + 1];
  r.z = lk(a2[c + 2] * t.z + b2[c + 2]) + asc[c + 2] * s.z + bsc[c + 2];
  r.w = lk(a2[c + 3] * t.w + b2[c + 3]) + asc[c + 3] * s.w + bsc[c + 3];
  ((float4*)o)[idx] = r;
}

// ---------------------------------------------------------------------------
// Counting sort of edges by e_query: hist -> scanA/B/C -> scatter
// ---------------------------------------------------------------------------
__global__ __launch_bounds__(256) void hist_k(const int* __restrict__ eq, int* __restrict__ cnt) {
  const int stride = gridDim.x << 8;
  for (int e = (blockIdx.x << 8) + threadIdx.x; e < EDG; e += stride)
    atomicAdd(&cnt[eq[e]], 1);
}

__global__ __launch_bounds__(256) void scanA_k(const int* __restrict__ cnt, int* __restrict__ part) {
  __shared__ int s[256];
  const int tid = threadIdx.x;
  const int base = blockIdx.x * SCH;
  int acc = 0;
  for (int i = tid; i < SCH; i += 256) {
    const int idx = base + i;
    if (idx < NP) acc += cnt[idx];
  }
  s[tid] = acc;
  __syncthreads();
  for (int d = 128; d > 0; d >>= 1) {
    if (tid < d) s[tid] += s[tid + d];
    __syncthreads();
  }
  if (tid == 0) part[blockIdx.x] = s[0];
}

__global__ void scanB_k(int* __restrict__ part, int* __restrict__ off) {
  if (threadIdx.x == 0) {
    int run = 0;
    for (int i = 0; i < SNB; ++i) { const int v = part[i]; part[i] = run; run += v; }
    off[NP] = EDG;
  }
}

__global__ __launch_bounds__(256) void scanC_k(const int* __restrict__ cnt,
                                               const int* __restrict__ part,
                                               int* __restrict__ off, int* __restrict__ cur) {
  __shared__ int s[256];
  const int tid = threadIdx.x;
  const int base = blockIdx.x * SCH + tid * 8;
  int loc[8];
  int mysum = 0;
#pragma unroll
  for (int j = 0; j < 8; ++j) {
    const int idx = base + j;
    const int v = (idx < NP) ? cnt[idx] : 0;
    loc[j] = mysum;
    mysum += v;
  }
  s[tid] = mysum;
  __syncthreads();
  // inclusive Hillis-Steele
  for (int d = 1; d < 256; d <<= 1) {
    int v = (tid >= d) ? s[tid - d] : 0;
    __syncthreads();
    s[tid] += v;
    __syncthreads();
  }
  const int tb = part[blockIdx.x] + s[tid] - mysum;
#pragma unroll
  for (int j = 0; j < 8; ++j) {
    const int idx = base + j;
    if (idx < NP) { off[idx] = tb + loc[j]; cur[idx] = tb + loc[j]; }
  }
}

__global__ __launch_bounds__(256) void scat_k(const int* __restrict__ er,
                                              const int* __restrict__ eq,
                                              int* __restrict__ cur, int* __restrict__ sref) {
  const int stride = gridDim.x << 8;
  for (int e = (blockIdx.x << 8) + threadIdx.x; e < EDG; e += stride) {
    const int p = atomicAdd(&cur[eq[e]], 1);
    sref[p] = er[e];
  }
}

// Pre-shuffle W_kp [15][64][64] fp32 into MFMA B-fragment order, bf16:
// Wf[(((k*2+kb)*4+nt)*64+lane)*8+j] = W[k][kb*32+(lane>>4)*8+j][nt*16+(lane&15)]
__global__ __launch_bounds__(256) void wsh_k(const float* __restrict__ Wkp, __bf16* __restrict__ Wf) {
  const int i = (blockIdx.x << 8) + threadIdx.x;
  if (i >= NK * 2 * 4 * 64 * 8) return;
  const int j = i & 7;
  const int lane = (i >> 3) & 63;
  const int nt = (i >> 9) & 3;
  const int kb = (i >> 11) & 1;
  const int k = i >> 12;
  const int kd = kb * 32 + ((lane >> 4) << 3) + j;
  const int n = nt * 16 + (lane & 15);
  Wf[i] = (__bf16)Wkp[(k * 64 + kd) * 64 + n];
}

// ---------------------------------------------------------------------------
// Fused KPConv (gather form): block = 16 queries, 256 threads.
// Phase A: accumulate agg[q][k][c] = sum_{edges of q} infl_k * h[ref][c]
//   (16 lanes per query; lane t<15 computes infl for kernel point t; active-k
//    set broadcast via __ballot; f gathered as float4 per lane; LDS RMW fp32,
//    atomic-free: each (q, c-chunk) owned by one lane.)
// Phase B: y[q][:] = sum_k agg[q][k][:] @ W_k via bf16 MFMA 16x16x32.
//   A-frag from LDS agg (fp32 -> bf16), B-frag preshuffled bf16 from L2.
// LDS = 16*15*68*4 = 65,280 B -> 2 blocks/CU.
// ---------------------------------------------------------------------------
__global__ __launch_bounds__(256) void kpagg_k(const float* __restrict__ pos,
                                               const int* __restrict__ sref,
                                               const int* __restrict__ off,
                                               const float* __restrict__ kpts,
                                               const __bf16* __restrict__ Wf,
                                               const float* __restrict__ h,
                                               float* __restrict__ y) {
  __shared__ float agg[16 * NK * AK];

  const int tid = threadIdx.x;
  const int q0 = blockIdx.x << 4;
  const int slot = tid >> 4;   // 0..15 query within block
  const int t = tid & 15;      // 0..15 c-chunk / kernel-point lane

  // zero agg
  for (int i = tid; i < 16 * NK * AK / 4; i += 256) ((float4*)agg)[i] = make_float4(0, 0, 0, 0);

  const int q = q0 + slot;
  const int e0 = off[q];
  const int e1 = off[q + 1];
  const float qx = pos[q * 4 + 1];
  const float qy = pos[q * 4 + 2];
  const float qz = pos[q * 4 + 3];
  float kx = 0.f, ky = 0.f, kz = 0.f;
  if (t < NK) { kx = kpts[t * 3 + 0]; ky = kpts[t * 3 + 1]; kz = kpts[t * 3 + 2]; }
  __syncthreads();

  float* aggq = &agg[slot * (NK * AK)];
  for (int e = e0; e < e1; ++e) {
    const int ref = sref[e];
    const float rx = pos[ref * 4 + 1] - qx;
    const float ry = pos[ref * 4 + 2] - qy;
    const float rz = pos[ref * 4 + 3] - qz;
    float w = 0.f;
    if (t < NK) {
      const float dx = rx - kx, dy = ry - ky, dz = rz - kz;
      w = 1.f - sqrtf(dx * dx + dy * dy + dz * dz) * (1.f / SIGK);
      if (w < 0.f) w = 0.f;
    }
    const unsigned long long bal = __ballot(w > 0.f);
    unsigned m = (unsigned)((bal >> (tid & 48)) & 0x7FFFu);
    const float4 f4 = *(const float4*)&h[(size_t)ref * 64 + t * 4];
    while (m) {
      const int k = __builtin_ctz(m);
      m &= m - 1;
      const float wk = __shfl(w, (tid & 48) | k, 64);
      float* a = &aggq[k * AK + t * 4];
      float4 v = *(float4*)a;
      v.x += wk * f4.x; v.y += wk * f4.y; v.z += wk * f4.z; v.w += wk * f4.w;
      *(float4*)a = v;
    }
  }
  __syncthreads();

  // Phase B: MFMA. 4 waves, wave w handles cols [w*16, w*16+16).
  const int wave = tid >> 6;
  const int lane = tid & 63;
  const int mrow = lane & 15;          // A m-index
  const int kq = lane >> 4;            // quad
  v4f acc = {0.f, 0.f, 0.f, 0.f};
  const v8bf* Wf8 = (const v8bf*)Wf;
#pragma unroll
  for (int k = 0; k < NK; ++k) {
#pragma unroll
    for (int kb = 0; kb < 2; ++kb) {
      const float* ap = &agg[mrow * (NK * AK) + k * AK + kb * 32 + (kq << 3)];
      const float4 al = *(const float4*)ap;
      const float4 ah = *(const float4*)(ap + 4);
      v8bf av;
      av[0] = (__bf16)al.x; av[1] = (__bf16)al.y; av[2] = (__bf16)al.z; av[3] = (__bf16)al.w;
      av[4] = (__bf16)ah.x; av[5] = (__bf16)ah.y; av[6] = (__bf16)ah.z; av[7] = (__bf16)ah.w;
      const v8bf bv = Wf8[((k * 2 + kb) * 4 + wave) * 64 + lane];
      acc = __builtin_amdgcn_mfma_f32_16x16x32_bf16(av, bv, acc, 0, 0, 0);
    }
  }
  // C/D layout: col = lane&15, row = (lane>>4)*4 + reg
#pragma unroll
  for (int r = 0; r < 4; ++r) {
    const int row = (lane >> 4) * 4 + r;
    const int col = wave * 16 + (lane & 15);
    y[(size_t)(q0 + row) * 64 + col] = acc[r];
  }
}

// ---------------------------------------------------------------------------
extern "C" void kernel_launch(void* const* d_in, const int* in_sizes, int n_in,
                              void* d_out, int out_size, void* d_ws, size_t ws_size,
                              hipStream_t stream) {
  const float* pos = (const float*)d_in[0];
  const float* x   = (const float*)d_in[1];
  const int* er    = (const int*)d_in[2];
  const int* eq    = (const int*)d_in[3];
  const float* W1  = (const float*)d_in[4];
  const float* g1  = (const float*)d_in[5];
  const float* b1  = (const float*)d_in[6];
  const float* kp  = (const float*)d_in[7];
  const float* Wkp = (const float*)d_in[8];
  const float* gkp = (const float*)d_in[9];
  const float* bkp = (const float*)d_in[10];
  const float* W2  = (const float*)d_in[11];
  const float* g2  = (const float*)d_in[12];
  const float* b2  = (const float*)d_in[13];
  const float* Wsc = (const float*)d_in[14];
  const float* gsc = (const float*)d_in[15];
  const float* bsc = (const float*)d_in[16];
  float* out = (float*)d_out;
  float* ws = (float*)d_ws;

  // small stats/affine block
  float* sum1 = ws;          float* sq1  = ws + 64;
  float* sumsc = ws + 128;   float* sqsc = ws + 384;
  float* sumy = ws + 640;    float* sqy  = ws + 704;
  float* sum2 = ws + 768;    float* sq2  = ws + 1024;
  float* a1v = ws + 1280;    float* b1v  = ws + 1344;
  float* ascv = ws + 1408;   float* bscv = ws + 1664;
  float* ayv = ws + 1920;    float* byv  = ws + 1984;
  float* a2v = ws + 2048;    float* b2v  = ws + 2304;

  float* ybuf = ws + 4096;                  // [N,64]
  float* hbuf = ybuf + (size_t)NP * 64;     // [N,64]
  float* T    = hbuf + (size_t)NP * 64;     // big region: sort bufs, later tsc
  // sort buffers live inside T (freed before tsc is written)
  int* cnt  = (int*)T;
  int* off  = cnt + 100352;
  int* cur  = off + 100352;
  int* part = cur + 100352;
  int* sref = part + 256;
  __bf16* Wf = (__bf16*)(sref + EDG);
  float* tsc = T;                           // [N,256], written after kpagg

  const float invn = 1.f / (float)NP;

  (void)hipMemsetAsync(ws, 0, 4096 * sizeof(float), stream);
  (void)hipMemsetAsync(cnt, 0, 100352 * sizeof(int), stream);

  // unary_1: h = leaky(BN(x@W1))
  gemm_k<128, false><<<dim3(1563, 1), 256, 0, stream>>>(x, W1, hbuf, NP, 64, nullptr, nullptr);
  colstats_k<64><<<512, 256, 0, stream>>>(hbuf, NP * 64, sum1, sq1);
  finalize_k<<<1, 256, 0, stream>>>(sum1, sq1, g1, b1, a1v, b1v, 64, invn);
  normleaky_k<<<6250, 256, 0, stream>>>(hbuf, a1v, b1v);

  // counting sort of edges by query + W preshuffle
  hist_k<<<2048, 256, 0, stream>>>(eq, cnt);
  scanA_k<<<SNB, 256, 0, stream>>>(cnt, part);
  scanB_k<<<1, 64, 0, stream>>>(part, off);
  scanC_k<<<SNB, 256, 0, stream>>>(cnt, part, off, cur);
  scat_k<<<2048, 256, 0, stream>>>(er, eq, cur, sref);
  wsh_k<<<240, 256, 0, stream>>>(Wkp, Wf);

  // fused KPConv gather + MFMA GEMM
  kpagg_k<<<6250, 256, 0, stream>>>(pos, sref, off, kp, Wf, hbuf, ybuf);
  colstats_k<64><<<512, 256, 0, stream>>>(ybuf, NP * 64, sumy, sqy);
  finalize_k<<<1, 256, 0, stream>>>(sumy, sqy, gkp, bkp, ayv, byv, 64, invn);

  // unary_2: t2 = leaky(BN(y)) @ W2 -> staged in d_out
  gemm_k<64, true><<<dim3(1563, 4), 256, 0, stream>>>(ybuf, W2, out, NP, 256, ayv, byv);
  colstats_k<256><<<512, 256, 0, stream>>>(out, NP * 256, sum2, sq2);
  finalize_k<<<1, 256, 0, stream>>>(sum2, sq2, g2, b2, a2v, b2v, 256, invn);

  // shortcut: tsc = x@Wsc (after kpagg so tsc can overlay sort buffers)
  gemm_k<128, false><<<dim3(1563, 4), 256, 0, stream>>>(x, Wsc, tsc, NP, 256, nullptr, nullptr);
  colstats_k<256><<<512, 256, 0, stream>>>(tsc, NP * 256, sumsc, sqsc);
  finalize_k<<<1, 256, 0, stream>>>(sumsc, sqsc, gsc, bsc, ascv, bscv, 256, invn);

  // out = leaky(BN(t2)) + BN(tsc)
  final_k<<<25000, 256, 0, stream>>>(out, tsc, a2v, b2v, ascv, bscv);
}